// Round 7
// baseline (42739.090 us; speedup 1.0000x reference)
//
#include <hip/hip_runtime.h>
#include <cstdint>
#include <cstddef>

static const int kT = 1000;
static const int kM = 16000;          // 16 * 1000 tokens
#define MASKVF (-1000000000.0f)
#define SELFVF (-50000.0f)
#define RSD     0.17677669529663687f  // 32^-0.5

// ============================================================
// Row GEMM (np-f32 mimic): one block per row, 256 threads over N.
// f32 storage, stripe-4 f32 accumulation (BLAS-flavored).
// EPI: 0 none, 1 exact GELU (f64 erf like np upcast), 2 posenc add
//      (f32 arg grid t*div, f64 sin/cos of that f32 arg).
// ============================================================
template<int EPI>
__global__ __launch_bounds__(256)
void k_rowgemm(const float* __restrict__ A, const float* __restrict__ W,
               const float* __restrict__ bias, float* __restrict__ C,
               int N, int K, int ldc)
{
    __shared__ float As[256];
    const int row = blockIdx.x;
    const int n = threadIdx.x;
    for (int k = n; k < K; k += 256) As[k] = A[(size_t)row * K + k];
    __syncthreads();
    if (n >= N) return;
    float a0 = 0.f, a1 = 0.f, a2 = 0.f, a3 = 0.f;
    int k = 0;
    for (; k + 3 < K; k += 4) {
        a0 = fmaf(As[k + 0], W[(size_t)(k + 0) * N + n], a0);
        a1 = fmaf(As[k + 1], W[(size_t)(k + 1) * N + n], a1);
        a2 = fmaf(As[k + 2], W[(size_t)(k + 2) * N + n], a2);
        a3 = fmaf(As[k + 3], W[(size_t)(k + 3) * N + n], a3);
    }
    for (; k < K; ++k) a0 = fmaf(As[k], W[(size_t)k * N + n], a0);
    float acc = (a0 + a1) + (a2 + a3);
    if (bias) acc += bias[n];
    if (EPI == 1) acc = 0.5f * acc * (1.0f + (float)erf((double)acc * 0.7071067811865476));
    if (EPI == 2) {
        int t = row % kT;
        const float cexp = (float)(-9.21034037198 / 256.0);
        float dv = expf((float)(n & ~1) * cexp);
        float arg = (float)t * dv;                  // f32 grid like np pos*div
        acc += (n & 1) ? (float)cos((double)arg) : (float)sin((double)arg);
    }
    C[(size_t)row * ldc + n] = acc;
}

// ============================================================
// Embedding gather + mask
// ============================================================
__global__ __launch_bounds__(128)
void k_embed(const int* __restrict__ mcc, const int* __restrict__ amt,
             const int* __restrict__ cur,
             const float* __restrict__ e_mcc, const float* __restrict__ e_amt,
             const float* __restrict__ e_cur,
             float* __restrict__ emb, int* __restrict__ maskbuf)
{
    int tok = blockIdx.x;
    int c = threadIdx.x;
    if (c < 112) {
        float v;
        if (c < 64)       v = e_mcc[mcc[tok] * 64 + c];
        else if (c < 96)  v = e_amt[amt[tok] * 32 + (c - 64)];
        else              v = e_cur[cur[tok] * 16 + (c - 96)];
        emb[(size_t)tok * 112 + c] = v;
    }
    if (c == 0) maskbuf[tok] = (mcc[tok] == 0) ? 1 : 0;
}

// ============================================================
// LayerNorm(x + delta), f32 mimic: one thread per token,
// stripe-4 sums, division (not reciprocal-mult).
// ============================================================
__global__ __launch_bounds__(256)
void k_ln(const float* __restrict__ x, const float* __restrict__ dlt,
          const float* __restrict__ g, const float* __restrict__ b,
          float* __restrict__ out)
{
    int tok = blockIdx.x * 256 + threadIdx.x;
    if (tok >= kM) return;
    const float* xr = x + (size_t)tok * 256;
    const float* dr = dlt + (size_t)tok * 256;
    float s0 = 0.f, s1 = 0.f, s2 = 0.f, s3 = 0.f;
    for (int i = 0; i < 256; i += 4) {
        s0 += xr[i + 0] + dr[i + 0];
        s1 += xr[i + 1] + dr[i + 1];
        s2 += xr[i + 2] + dr[i + 2];
        s3 += xr[i + 3] + dr[i + 3];
    }
    float mean = ((s0 + s1) + (s2 + s3)) / 256.0f;
    float v0 = 0.f, v1 = 0.f, v2 = 0.f, v3 = 0.f;
    for (int i = 0; i < 256; i += 4) {
        float d0 = xr[i + 0] + dr[i + 0] - mean; v0 = fmaf(d0, d0, v0);
        float d1 = xr[i + 1] + dr[i + 1] - mean; v1 = fmaf(d1, d1, v1);
        float d2 = xr[i + 2] + dr[i + 2] - mean; v2 = fmaf(d2, d2, v2);
        float d3 = xr[i + 3] + dr[i + 3] - mean; v3 = fmaf(d3, d3, v3);
    }
    float var = ((v0 + v1) + (v2 + v3)) / 256.0f;
    float denom = sqrtf(var + 1e-5f);
    float* yo = out + (size_t)tok * 256;
    for (int i = 0; i < 256; ++i)
        yo[i] = (xr[i] + dr[i] - mean) / denom * g[i] + b[i];
}

// ============================================================
// f32 dot helpers mirroring the reference's elementwise rounding:
// local: qs = q*RSD (rounded), kn = k/max(norm,1e-12) (rounded), dot.
// lsh:   dot(q_raw, kn) then *RSD after.
// ============================================================
__device__ inline float knorm32(const float* kr)
{
    float n0 = 0.f, n1 = 0.f, n2 = 0.f, n3 = 0.f;
    for (int d = 0; d < 32; d += 4) {
        n0 = fmaf(kr[d + 0], kr[d + 0], n0);
        n1 = fmaf(kr[d + 1], kr[d + 1], n1);
        n2 = fmaf(kr[d + 2], kr[d + 2], n2);
        n3 = fmaf(kr[d + 3], kr[d + 3], n3);
    }
    return fmaxf(sqrtf((n0 + n1) + (n2 + n3)), 1e-12f);
}

__device__ inline float dot32_kn(const float* q, const float* kr, float nm)
{
    float a0 = 0.f, a1 = 0.f, a2 = 0.f, a3 = 0.f;
    for (int d = 0; d < 32; d += 4) {
        a0 = fmaf(q[d + 0], kr[d + 0] / nm, a0);
        a1 = fmaf(q[d + 1], kr[d + 1] / nm, a1);
        a2 = fmaf(q[d + 2], kr[d + 2] / nm, a2);
        a3 = fmaf(q[d + 3], kr[d + 3] / nm, a3);
    }
    return (a0 + a1) + (a2 + a3);
}

// ============================================================
// Local attention (f32 mimic): one thread per (bm, ti).
// ============================================================
__global__ __launch_bounds__(256)
void k_local(const float* __restrict__ qk, const float* __restrict__ v,
             const int* __restrict__ mask, float* __restrict__ attnout)
{
    int idx = blockIdx.x * 256 + threadIdx.x;
    if (idx >= 64 * 1000) return;
    const int ti = idx % 1000;
    const int bm = idx / 1000;
    const int b = bm >> 2, h = bm & 3;
    const int wi = ti / 50;
    const bool mi = mask[b * kT + ti] != 0;

    float qs[32];
    {
        const float* qr = qk + ((size_t)(b * kT + ti)) * 256 + h * 32;
        for (int d = 0; d < 32; ++d) qs[d] = qr[d] * RSD;   // bq = q * D^-0.5 (pre-rounded)
    }

    auto tj_of = [&](int j) -> int {
        if (j < 50) return (wi > 0) ? (wi - 1) * 50 + j : -1;
        return wi * 50 + (j - 50);
    };
    auto dval = [&](int j) -> float {
        int tj = tj_of(j);
        bool mj = (tj >= 0) && (mask[b * kT + tj] != 0);
        if (!(mi && mj)) return MASKVF;
        if (tj < 0)      return MASKVF;
        if (ti == tj)    return SELFVF;
        if (ti < tj)     return MASKVF;
        const float* kr = qk + ((size_t)(b * kT + tj)) * 256 + h * 32;
        float nm = knorm32(kr);
        return dot32_kn(qs, kr, nm);
    };

    float m = -3.4e38f;
    for (int j = 0; j < 100; ++j) m = fmaxf(m, dval(j));
    float e0 = 0.f, e1 = 0.f, e2 = 0.f, e3 = 0.f;
    for (int j = 0; j < 100; j += 4) {
        e0 += expf(dval(j + 0) - m);
        e1 += expf(dval(j + 1) - m);
        e2 += expf(dval(j + 2) - m);
        e3 += expf(dval(j + 3) - m);
    }
    float ssum = (e0 + e1) + (e2 + e3);

    float o[32];
    for (int d = 0; d < 32; ++d) o[d] = 0.f;
    for (int j = 0; j < 100; ++j) {
        float p = expf(dval(j) - m) / ssum;
        int tj = tj_of(j);
        if (tj >= 0) {
            const float* vr = v + ((size_t)(b * kT + tj)) * 256 + h * 32;
            for (int d = 0; d < 32; ++d) o[d] = fmaf(p, vr[d], o[d]);
        }
    }
    float* op = attnout + ((size_t)(b * kT + ti)) * 256 + h * 32;
    for (int d = 0; d < 32; ++d) op[d] = o[d];
}

// ============================================================
// LSH bucketing (f32 stripe-4): one thread per (bm, h, t). rot [32][8][20].
// ============================================================
__global__ __launch_bounds__(256)
void k_bucket(const float* __restrict__ qk, const float* __restrict__ rot,
              int* __restrict__ bkt)
{
    int idx = blockIdx.x * 256 + threadIdx.x;
    if (idx >= 64 * 8 * 1000) return;
    const int t = idx % 1000;
    const int h = (idx / 1000) & 7;
    const int bm = idx / 8000;
    const int b = bm >> 2, hs = bm & 3;
    const float* q = qk + ((size_t)(b * kT + t)) * 256 + (4 + hs) * 32;
    float qr[32];
    for (int d = 0; d < 32; ++d) qr[d] = q[d];
    float s[20];
    for (int r = 0; r < 20; ++r) {
        float a0 = 0.f, a1 = 0.f, a2 = 0.f, a3 = 0.f;
        for (int d = 0; d < 32; d += 4) {
            a0 = fmaf(qr[d + 0], rot[(d + 0) * 160 + h * 20 + r], a0);
            a1 = fmaf(qr[d + 1], rot[(d + 1) * 160 + h * 20 + r], a1);
            a2 = fmaf(qr[d + 2], rot[(d + 2) * 160 + h * 20 + r], a2);
            a3 = fmaf(qr[d + 3], rot[(d + 3) * 160 + h * 20 + r], a3);
        }
        s[r] = (a0 + a1) + (a2 + a3);
    }
    float best = -3.4e38f; int bi = 0;
    for (int r = 0; r < 40; ++r) {
        float val = (r < 20) ? s[r] : -s[r - 20];
        if (val > best) { best = val; bi = r; }
    }
    bkt[(bm * 8 + h) * 1000 + t] = bi;
}

// ============================================================
// Counting sort per (bm, h): literal stable (bucket, t) order.
// ============================================================
__global__ __launch_bounds__(64)
void k_sortn(const int* __restrict__ bkt, int* __restrict__ st)
{
    int bh = blockIdx.x * 64 + threadIdx.x;
    if (bh >= 512) return;
    const int* src = bkt + bh * 1000;
    int* dst = st + bh * 1000;
    int pos = 0;
    for (int beta = 0; beta < 40; ++beta)
        for (int t = 0; t < 1000; ++t)
            if (src[t] == beta) dst[pos++] = t;
}

// ============================================================
// LSH lse (f32 mimic): one thread per (bm, slot).
// ============================================================
__global__ __launch_bounds__(256)
void k_lsh_lse(const float* __restrict__ qk, const int* __restrict__ st,
               const int* __restrict__ mask, float* __restrict__ lsebuf)
{
    int idx = blockIdx.x * 256 + threadIdx.x;
    if (idx >= 64 * 8000) return;
    const int s = idx % 8000;
    const int bm = idx / 8000;
    const int b = bm >> 2, hs = bm & 3;
    const int c = s / 25;
    const int h = c / 40;
    const int cp = (c + 319) % 320;
    const int* stb = st + bm * 8000;
    const int tqi = stb[s];
    const bool mi = mask[b * kT + tqi] != 0;
    float qr[32];
    {
        const float* q = qk + ((size_t)(b * kT + tqi)) * 256 + (4 + hs) * 32;
        for (int d = 0; d < 32; ++d) qr[d] = q[d];
    }

    auto dval = [&](int j) -> float {
        int slot = (j < 25) ? c * 25 + j : cp * 25 + (j - 25);
        int tj = stb[slot];
        if (tqi == tj) return SELFVF;
        if (tqi < tj)  return MASKVF;
        bool mj = mask[b * kT + tj] != 0;
        if (!(mi && mj)) return MASKVF;
        const float* kr = qk + ((size_t)(b * kT + tj)) * 256 + (4 + hs) * 32;
        float nm = knorm32(kr);
        return dot32_kn(qr, kr, nm) * RSD;    // scale AFTER dot (ref order)
    };

    float m = -3.4e38f;
    for (int j = 0; j < 50; ++j) m = fmaxf(m, dval(j));
    float e0 = 0.f, e1 = 0.f;
    for (int j = 0; j < 50; j += 2) {
        e0 += expf(dval(j + 0) - m);
        e1 += expf(dval(j + 1) - m);
    }
    lsebuf[(bm * 8 + h) * 1000 + tqi] = m + logf(e0 + e1);
}

// ============================================================
// LSH output per hash slot (f32, no atomics): o_lsh[(bm*8+h)*1000+t][d]
// ============================================================
__global__ __launch_bounds__(256)
void k_lsh_out(const float* __restrict__ qk, const float* __restrict__ v,
               const int* __restrict__ st, const int* __restrict__ mask,
               const float* __restrict__ lsebuf, float* __restrict__ o_lsh)
{
    int idx = blockIdx.x * 256 + threadIdx.x;
    if (idx >= 64 * 8000) return;
    const int s = idx % 8000;
    const int bm = idx / 8000;
    const int b = bm >> 2, hs = bm & 3;
    const int c = s / 25;
    const int h = c / 40;
    const int cp = (c + 319) % 320;
    const int* stb = st + bm * 8000;
    const int tqi = stb[s];
    const bool mi = mask[b * kT + tqi] != 0;
    float qr[32];
    {
        const float* q = qk + ((size_t)(b * kT + tqi)) * 256 + (4 + hs) * 32;
        for (int d = 0; d < 32; ++d) qr[d] = q[d];
    }
    const float lse = lsebuf[(bm * 8 + h) * 1000 + tqi];

    float o[32];
    for (int d = 0; d < 32; ++d) o[d] = 0.f;
    for (int j = 0; j < 50; ++j) {
        int slot = (j < 25) ? c * 25 + j : cp * 25 + (j - 25);
        int tj = stb[slot];
        float dv;
        if (tqi == tj)      dv = SELFVF;
        else if (tqi < tj)  dv = MASKVF;
        else {
            bool mj = mask[b * kT + tj] != 0;
            if (!(mi && mj)) dv = MASKVF;
            else {
                const float* kr = qk + ((size_t)(b * kT + tj)) * 256 + (4 + hs) * 32;
                float nm = knorm32(kr);
                dv = dot32_kn(qr, kr, nm) * RSD;
            }
        }
        float p = expf(dv - lse);
        const float* vr = v + ((size_t)(b * kT + tj)) * 256 + (4 + hs) * 32;
        for (int d = 0; d < 32; ++d) o[d] = fmaf(p, vr[d], o[d]);
    }
    float* op = o_lsh + (((size_t)bm * 8 + h) * 1000 + tqi) * 32;
    for (int d = 0; d < 32; ++d) op[d] = o[d];
}

// ============================================================
// Combine 8 hashes (L2R like ref) -> attnbuf cols 128..255
// ============================================================
__global__ __launch_bounds__(256)
void k_combine(const float* __restrict__ o_lsh, const float* __restrict__ lsebuf,
               float* __restrict__ attnout)
{
    int idx = blockIdx.x * 256 + threadIdx.x;
    if (idx >= 64 * 1000 * 32) return;
    int d = idx & 31;
    int t = (idx >> 5) % 1000;
    int bm = idx / 32000;
    int b = bm >> 2, hs = bm & 3;
    float l[8];
    float m = -3.4e38f;
    for (int hh = 0; hh < 8; ++hh) {
        l[hh] = lsebuf[(bm * 8 + hh) * 1000 + t];
        m = fmaxf(m, l[hh]);
    }
    float ssum = 0.f;
    for (int hh = 0; hh < 8; ++hh) ssum += expf(l[hh] - m);
    float lse_tot = m + logf(ssum);
    float acc = 0.f;
    for (int hh = 0; hh < 8; ++hh) {
        float w = expf(l[hh] - lse_tot);
        acc = fmaf(w, o_lsh[(((size_t)bm * 8 + hh) * 1000 + t) * 32 + d], acc);
    }
    attnout[((size_t)(b * kT + t)) * 256 + (4 + hs) * 32 + d] = acc;
}

// ============================================================
// Host launcher
// ============================================================
static inline void rowgemm(int epi, const float* A, const float* W,
                           const float* bias, float* C, int M, int N, int K, int ldc,
                           hipStream_t s)
{
    dim3 g(M);
    if (epi == 0)      hipLaunchKernelGGL((k_rowgemm<0>), g, dim3(256), 0, s, A, W, bias, C, N, K, ldc);
    else if (epi == 1) hipLaunchKernelGGL((k_rowgemm<1>), g, dim3(256), 0, s, A, W, bias, C, N, K, ldc);
    else               hipLaunchKernelGGL((k_rowgemm<2>), g, dim3(256), 0, s, A, W, bias, C, N, K, ldc);
}

extern "C" void kernel_launch(void* const* d_in, const int* in_sizes, int n_in,
                              void* d_out, int out_size, void* d_ws, size_t ws_size,
                              hipStream_t stream)
{
    const int*   mcc     = (const int*)d_in[0];
    const int*   amt     = (const int*)d_in[1];
    const int*   cur     = (const int*)d_in[2];
    const float* e_mcc   = (const float*)d_in[3];
    const float* e_amt   = (const float*)d_in[4];
    const float* e_cur   = (const float*)d_in[5];
    const float* proj_w  = (const float*)d_in[6];
    const float* proj_b  = (const float*)d_in[7];
    const float* toqk_w  = (const float*)d_in[8];
    const float* tov_w   = (const float*)d_in[9];
    const float* toout_w = (const float*)d_in[10];
    const float* toout_b = (const float*)d_in[11];
    const float* ff1_w   = (const float*)d_in[12];
    const float* ff1_b   = (const float*)d_in[13];
    const float* ff2_w   = (const float*)d_in[14];
    const float* ff2_b   = (const float*)d_in[15];
    const float* ln1_g   = (const float*)d_in[16];
    const float* ln1_b   = (const float*)d_in[17];
    const float* ln2_g   = (const float*)d_in[18];
    const float* ln2_b   = (const float*)d_in[19];
    const float* rot     = (const float*)d_in[20];
    const float* hw1_mcc = (const float*)d_in[21];
    const float* hb1_mcc = (const float*)d_in[22];
    const float* hw2_mcc = (const float*)d_in[23];
    const float* hb2_mcc = (const float*)d_in[24];
    const float* hw1_amt = (const float*)d_in[25];
    const float* hb1_amt = (const float*)d_in[26];
    const float* hw2_amt = (const float*)d_in[27];
    const float* hb2_amt = (const float*)d_in[28];
    const float* hw1_cur = (const float*)d_in[29];
    const float* hb1_cur = (const float*)d_in[30];
    const float* hw2_cur = (const float*)d_in[31];
    const float* hb2_cur = (const float*)d_in[32];
    float* out = (float*)d_out;

    // ---- workspace carve (~169 MB f32, matches r1 budget which ran; no aliasing) ----
    char* p = (char*)d_ws;
    auto alloc = [&](size_t bytes) -> void* {
        void* r = (void*)p;
        p += (bytes + 255) & ~(size_t)255;
        return r;
    };
    float* xbuf    = (float*)alloc((size_t)kM * 256 * 4);
    float* ybuf    = (float*)alloc((size_t)kM * 256 * 4);
    float* qkbuf   = (float*)alloc((size_t)kM * 256 * 4);
    float* vbuf    = (float*)alloc((size_t)kM * 256 * 4);
    float* attnbuf = (float*)alloc((size_t)kM * 256 * 4);
    float* embbuf  = (float*)alloc((size_t)kM * 112 * 4);
    float* ffh     = (float*)alloc((size_t)kM * 128 * 4);
    float* o_lsh   = (float*)alloc((size_t)64 * 8 * 1000 * 32 * 4);
    float* lsebuf  = (float*)alloc((size_t)64 * 8000 * 4);
    int*   maskbuf = (int*)alloc((size_t)kM * 4);
    int*   bktbuf  = (int*)alloc((size_t)64 * 8000 * 4);
    int*   stbuf   = (int*)alloc((size_t)64 * 8000 * 4);
    (void)ws_size; (void)in_sizes; (void)n_in; (void)out_size;

    // ---- embed + projection(+posenc) ----
    hipLaunchKernelGGL(k_embed, dim3(kM), dim3(128), 0, stream,
                       mcc, amt, cur, e_mcc, e_amt, e_cur, embbuf, maskbuf);
    rowgemm(2, embbuf, proj_w, proj_b, xbuf, kM, 256, 112, 256, stream);

    // ---- layers ----
    for (int l = 0; l < 6; ++l) {
        const float* Wqk = toqk_w + (size_t)l * 256 * 256;
        const float* Wv  = tov_w + (size_t)l * 256 * 256;
        const float* Wo  = toout_w + (size_t)l * 256 * 256;
        const float* bo  = toout_b + (size_t)l * 256;
        const float* W1  = ff1_w + (size_t)l * 256 * 128;
        const float* b1  = ff1_b + (size_t)l * 128;
        const float* W2  = ff2_w + (size_t)l * 128 * 256;
        const float* b2  = ff2_b + (size_t)l * 256;
        const float* rl  = rot + (size_t)l * 32 * 8 * 20;

        rowgemm(0, xbuf, Wqk, nullptr, qkbuf, kM, 256, 256, 256, stream);
        rowgemm(0, xbuf, Wv, nullptr, vbuf, kM, 256, 256, 256, stream);

        hipLaunchKernelGGL(k_local, dim3((64 * 1000 + 255) / 256), dim3(256), 0, stream,
                           qkbuf, vbuf, maskbuf, attnbuf);
        hipLaunchKernelGGL(k_bucket, dim3((64 * 8000 + 255) / 256), dim3(256), 0, stream,
                           qkbuf, rl, bktbuf);
        hipLaunchKernelGGL(k_sortn, dim3(8), dim3(64), 0, stream, bktbuf, stbuf);
        hipLaunchKernelGGL(k_lsh_lse, dim3((64 * 8000 + 255) / 256), dim3(256), 0, stream,
                           qkbuf, stbuf, maskbuf, lsebuf);
        hipLaunchKernelGGL(k_lsh_out, dim3((64 * 8000 + 255) / 256), dim3(256), 0, stream,
                           qkbuf, vbuf, stbuf, maskbuf, lsebuf, o_lsh);
        hipLaunchKernelGGL(k_combine, dim3((64 * 1000 * 32 + 255) / 256), dim3(256), 0, stream,
                           o_lsh, lsebuf, attnbuf);

        rowgemm(0, attnbuf, Wo, bo, ybuf, kM, 256, 256, 256, stream);
        hipLaunchKernelGGL(k_ln, dim3((kM + 255) / 256), dim3(256), 0, stream,
                           xbuf, ybuf, ln1_g + l * 256, ln1_b + l * 256, xbuf);

        rowgemm(1, xbuf, W1, b1, ffh, kM, 128, 256, 128, stream);
        rowgemm(0, ffh, W2, b2, ybuf, kM, 256, 128, 256, stream);
        hipLaunchKernelGGL(k_ln, dim3((kM + 255) / 256), dim3(256), 0, stream,
                           xbuf, ybuf, ln2_g + l * 256, ln2_b + l * 256, xbuf);
    }

    // ---- heads ----
    rowgemm(1, xbuf, hw1_mcc, hb1_mcc, ffh, kM, 128, 256, 128, stream);
    rowgemm(0, ffh, hw2_mcc, hb2_mcc, out + 0, kM, 200, 128, 320, stream);
    rowgemm(1, xbuf, hw1_amt, hb1_amt, ffh, kM, 128, 256, 128, stream);
    rowgemm(0, ffh, hw2_amt, hb2_amt, out + 200, kM, 100, 128, 320, stream);
    rowgemm(1, xbuf, hw1_cur, hb1_cur, ffh, kM, 128, 256, 128, stream);
    rowgemm(0, ffh, hw2_cur, hb2_cur, out + 300, kM, 20, 128, 320, stream);
}

// Round 8
// 7224.912 us; speedup vs baseline: 5.9155x; 5.9155x over previous
//
#include <hip/hip_runtime.h>
#include <cstdint>
#include <cstddef>

static const int kT = 1000;
static const int kM = 16000;          // 16 * 1000 tokens
#define MASKVF (-1000000000.0f)
#define SELFVF (-50000.0f)
#define RSD     0.17677669529663687f  // 32^-0.5

// ============================================================
// Row GEMM (np-f32 mimic): one block per row, 256 threads over N.
// f32 storage, stripe-4 f32 accumulation (BLAS-flavored).
// EPI: 0 none, 1 exact GELU (f64 erf like np upcast), 2 posenc add
//      (f32 arg grid t*div, f64 sin/cos of that f32 arg).
// *** ARITHMETIC FROZEN: passing config (r7). Do not alter FP ops. ***
// ============================================================
template<int EPI>
__global__ __launch_bounds__(256)
void k_rowgemm(const float* __restrict__ A, const float* __restrict__ W,
               const float* __restrict__ bias, float* __restrict__ C,
               int N, int K, int ldc)
{
    __shared__ float As[256];
    const int row = blockIdx.x;
    const int n = threadIdx.x;
    for (int k = n; k < K; k += 256) As[k] = A[(size_t)row * K + k];
    __syncthreads();
    if (n >= N) return;
    float a0 = 0.f, a1 = 0.f, a2 = 0.f, a3 = 0.f;
    int k = 0;
    for (; k + 3 < K; k += 4) {
        a0 = fmaf(As[k + 0], W[(size_t)(k + 0) * N + n], a0);
        a1 = fmaf(As[k + 1], W[(size_t)(k + 1) * N + n], a1);
        a2 = fmaf(As[k + 2], W[(size_t)(k + 2) * N + n], a2);
        a3 = fmaf(As[k + 3], W[(size_t)(k + 3) * N + n], a3);
    }
    for (; k < K; ++k) a0 = fmaf(As[k], W[(size_t)k * N + n], a0);
    float acc = (a0 + a1) + (a2 + a3);
    if (bias) acc += bias[n];
    if (EPI == 1) acc = 0.5f * acc * (1.0f + (float)erf((double)acc * 0.7071067811865476));
    if (EPI == 2) {
        int t = row % kT;
        const float cexp = (float)(-9.21034037198 / 256.0);
        float dv = expf((float)(n & ~1) * cexp);
        float arg = (float)t * dv;                  // f32 grid like np pos*div
        acc += (n & 1) ? (float)cos((double)arg) : (float)sin((double)arg);
    }
    C[(size_t)row * ldc + n] = acc;
}

// ============================================================
// Embedding gather + mask
// ============================================================
__global__ __launch_bounds__(128)
void k_embed(const int* __restrict__ mcc, const int* __restrict__ amt,
             const int* __restrict__ cur,
             const float* __restrict__ e_mcc, const float* __restrict__ e_amt,
             const float* __restrict__ e_cur,
             float* __restrict__ emb, int* __restrict__ maskbuf)
{
    int tok = blockIdx.x;
    int c = threadIdx.x;
    if (c < 112) {
        float v;
        if (c < 64)       v = e_mcc[mcc[tok] * 64 + c];
        else if (c < 96)  v = e_amt[amt[tok] * 32 + (c - 64)];
        else              v = e_cur[cur[tok] * 16 + (c - 96)];
        emb[(size_t)tok * 112 + c] = v;
    }
    if (c == 0) maskbuf[tok] = (mcc[tok] == 0) ? 1 : 0;
}

// ============================================================
// LayerNorm(x + delta), f32 mimic (FROZEN arithmetic).
// ============================================================
__global__ __launch_bounds__(256)
void k_ln(const float* __restrict__ x, const float* __restrict__ dlt,
          const float* __restrict__ g, const float* __restrict__ b,
          float* __restrict__ out)
{
    int tok = blockIdx.x * 256 + threadIdx.x;
    if (tok >= kM) return;
    const float* xr = x + (size_t)tok * 256;
    const float* dr = dlt + (size_t)tok * 256;
    float s0 = 0.f, s1 = 0.f, s2 = 0.f, s3 = 0.f;
    for (int i = 0; i < 256; i += 4) {
        s0 += xr[i + 0] + dr[i + 0];
        s1 += xr[i + 1] + dr[i + 1];
        s2 += xr[i + 2] + dr[i + 2];
        s3 += xr[i + 3] + dr[i + 3];
    }
    float mean = ((s0 + s1) + (s2 + s3)) / 256.0f;
    float v0 = 0.f, v1 = 0.f, v2 = 0.f, v3 = 0.f;
    for (int i = 0; i < 256; i += 4) {
        float d0 = xr[i + 0] + dr[i + 0] - mean; v0 = fmaf(d0, d0, v0);
        float d1 = xr[i + 1] + dr[i + 1] - mean; v1 = fmaf(d1, d1, v1);
        float d2 = xr[i + 2] + dr[i + 2] - mean; v2 = fmaf(d2, d2, v2);
        float d3 = xr[i + 3] + dr[i + 3] - mean; v3 = fmaf(d3, d3, v3);
    }
    float var = ((v0 + v1) + (v2 + v3)) / 256.0f;
    float denom = sqrtf(var + 1e-5f);
    float* yo = out + (size_t)tok * 256;
    for (int i = 0; i < 256; ++i)
        yo[i] = (xr[i] + dr[i] - mean) / denom * g[i] + b[i];
}

// ============================================================
// f32 dot helpers (FROZEN): elementwise k/nm rounding then dot.
// ============================================================
__device__ inline float knorm32(const float* kr)
{
    float n0 = 0.f, n1 = 0.f, n2 = 0.f, n3 = 0.f;
    for (int d = 0; d < 32; d += 4) {
        n0 = fmaf(kr[d + 0], kr[d + 0], n0);
        n1 = fmaf(kr[d + 1], kr[d + 1], n1);
        n2 = fmaf(kr[d + 2], kr[d + 2], n2);
        n3 = fmaf(kr[d + 3], kr[d + 3], n3);
    }
    return fmaxf(sqrtf((n0 + n1) + (n2 + n3)), 1e-12f);
}

__device__ inline float dot32_kn(const float* q, const float* kr, float nm)
{
    float a0 = 0.f, a1 = 0.f, a2 = 0.f, a3 = 0.f;
    for (int d = 0; d < 32; d += 4) {
        a0 = fmaf(q[d + 0], kr[d + 0] / nm, a0);
        a1 = fmaf(q[d + 1], kr[d + 1] / nm, a1);
        a2 = fmaf(q[d + 2], kr[d + 2] / nm, a2);
        a3 = fmaf(q[d + 3], kr[d + 3] / nm, a3);
    }
    return (a0 + a1) + (a2 + a3);
}

// ============================================================
// Local attention (f32 mimic, FROZEN): one thread per (bm, ti).
// ============================================================
__global__ __launch_bounds__(256)
void k_local(const float* __restrict__ qk, const float* __restrict__ v,
             const int* __restrict__ mask, float* __restrict__ attnout)
{
    int idx = blockIdx.x * 256 + threadIdx.x;
    if (idx >= 64 * 1000) return;
    const int ti = idx % 1000;
    const int bm = idx / 1000;
    const int b = bm >> 2, h = bm & 3;
    const int wi = ti / 50;
    const bool mi = mask[b * kT + ti] != 0;

    float qs[32];
    {
        const float* qr = qk + ((size_t)(b * kT + ti)) * 256 + h * 32;
        for (int d = 0; d < 32; ++d) qs[d] = qr[d] * RSD;   // bq = q * D^-0.5 (pre-rounded)
    }

    auto tj_of = [&](int j) -> int {
        if (j < 50) return (wi > 0) ? (wi - 1) * 50 + j : -1;
        return wi * 50 + (j - 50);
    };
    auto dval = [&](int j) -> float {
        int tj = tj_of(j);
        bool mj = (tj >= 0) && (mask[b * kT + tj] != 0);
        if (!(mi && mj)) return MASKVF;
        if (tj < 0)      return MASKVF;
        if (ti == tj)    return SELFVF;
        if (ti < tj)     return MASKVF;
        const float* kr = qk + ((size_t)(b * kT + tj)) * 256 + h * 32;
        float nm = knorm32(kr);
        return dot32_kn(qs, kr, nm);
    };

    float m = -3.4e38f;
    for (int j = 0; j < 100; ++j) m = fmaxf(m, dval(j));
    float e0 = 0.f, e1 = 0.f, e2 = 0.f, e3 = 0.f;
    for (int j = 0; j < 100; j += 4) {
        e0 += expf(dval(j + 0) - m);
        e1 += expf(dval(j + 1) - m);
        e2 += expf(dval(j + 2) - m);
        e3 += expf(dval(j + 3) - m);
    }
    float ssum = (e0 + e1) + (e2 + e3);

    float o[32];
    for (int d = 0; d < 32; ++d) o[d] = 0.f;
    for (int j = 0; j < 100; ++j) {
        float p = expf(dval(j) - m) / ssum;
        int tj = tj_of(j);
        if (tj >= 0) {
            const float* vr = v + ((size_t)(b * kT + tj)) * 256 + h * 32;
            for (int d = 0; d < 32; ++d) o[d] = fmaf(p, vr[d], o[d]);
        }
    }
    float* op = attnout + ((size_t)(b * kT + ti)) * 256 + h * 32;
    for (int d = 0; d < 32; ++d) op[d] = o[d];
}

// ============================================================
// LSH bucketing (f32 stripe-4, FROZEN): one thread per (bm, h, t).
// ============================================================
__global__ __launch_bounds__(256)
void k_bucket(const float* __restrict__ qk, const float* __restrict__ rot,
              int* __restrict__ bkt)
{
    int idx = blockIdx.x * 256 + threadIdx.x;
    if (idx >= 64 * 8 * 1000) return;
    const int t = idx % 1000;
    const int h = (idx / 1000) & 7;
    const int bm = idx / 8000;
    const int b = bm >> 2, hs = bm & 3;
    const float* q = qk + ((size_t)(b * kT + t)) * 256 + (4 + hs) * 32;
    float qr[32];
    for (int d = 0; d < 32; ++d) qr[d] = q[d];
    float s[20];
    for (int r = 0; r < 20; ++r) {
        float a0 = 0.f, a1 = 0.f, a2 = 0.f, a3 = 0.f;
        for (int d = 0; d < 32; d += 4) {
            a0 = fmaf(qr[d + 0], rot[(d + 0) * 160 + h * 20 + r], a0);
            a1 = fmaf(qr[d + 1], rot[(d + 1) * 160 + h * 20 + r], a1);
            a2 = fmaf(qr[d + 2], rot[(d + 2) * 160 + h * 20 + r], a2);
            a3 = fmaf(qr[d + 3], rot[(d + 3) * 160 + h * 20 + r], a3);
        }
        s[r] = (a0 + a1) + (a2 + a3);
    }
    float best = -3.4e38f; int bi = 0;
    for (int r = 0; r < 40; ++r) {
        float val = (r < 20) ? s[r] : -s[r - 20];
        if (val > best) { best = val; bi = r; }
    }
    bkt[(bm * 8 + h) * 1000 + t] = bi;
}

// ============================================================
// Counting sort per (bm, h): PARALLEL LDS version (one block per bh).
// Output permutation bit-identical to the serial scan: stable
// (bucket, t) order. Pure integer logic — no FP.
// ============================================================
__global__ __launch_bounds__(64)
void k_sortp(const int* __restrict__ bkt, int* __restrict__ st)
{
    __shared__ int lb[1000];
    __shared__ int cnt[40];
    __shared__ int offs[40];
    const int bh = blockIdx.x;   // 0..511
    const int* src = bkt + bh * 1000;
    for (int i = threadIdx.x; i < 1000; i += 64) lb[i] = src[i];
    if (threadIdx.x < 40) cnt[threadIdx.x] = 0;
    __syncthreads();
    for (int i = threadIdx.x; i < 1000; i += 64) atomicAdd(&cnt[lb[i]], 1);
    __syncthreads();
    if (threadIdx.x == 0) {
        int a = 0;
        for (int q = 0; q < 40; ++q) { offs[q] = a; a += cnt[q]; }
    }
    __syncthreads();
    if (threadIdx.x < 40) {
        const int beta = threadIdx.x;
        int off = offs[beta];
        int* dst = st + bh * 1000;
        for (int t = 0; t < 1000; ++t)
            if (lb[t] == beta) dst[off++] = t;
    }
}

// ============================================================
// LSH lse (f32 mimic, FROZEN): one thread per (bm, slot).
// ============================================================
__global__ __launch_bounds__(256)
void k_lsh_lse(const float* __restrict__ qk, const int* __restrict__ st,
               const int* __restrict__ mask, float* __restrict__ lsebuf)
{
    int idx = blockIdx.x * 256 + threadIdx.x;
    if (idx >= 64 * 8000) return;
    const int s = idx % 8000;
    const int bm = idx / 8000;
    const int b = bm >> 2, hs = bm & 3;
    const int c = s / 25;
    const int h = c / 40;
    const int cp = (c + 319) % 320;
    const int* stb = st + bm * 8000;
    const int tqi = stb[s];
    const bool mi = mask[b * kT + tqi] != 0;
    float qr[32];
    {
        const float* q = qk + ((size_t)(b * kT + tqi)) * 256 + (4 + hs) * 32;
        for (int d = 0; d < 32; ++d) qr[d] = q[d];
    }

    auto dval = [&](int j) -> float {
        int slot = (j < 25) ? c * 25 + j : cp * 25 + (j - 25);
        int tj = stb[slot];
        if (tqi == tj) return SELFVF;
        if (tqi < tj)  return MASKVF;
        bool mj = mask[b * kT + tj] != 0;
        if (!(mi && mj)) return MASKVF;
        const float* kr = qk + ((size_t)(b * kT + tj)) * 256 + (4 + hs) * 32;
        float nm = knorm32(kr);
        return dot32_kn(qr, kr, nm) * RSD;    // scale AFTER dot (ref order)
    };

    float m = -3.4e38f;
    for (int j = 0; j < 50; ++j) m = fmaxf(m, dval(j));
    float e0 = 0.f, e1 = 0.f;
    for (int j = 0; j < 50; j += 2) {
        e0 += expf(dval(j + 0) - m);
        e1 += expf(dval(j + 1) - m);
    }
    lsebuf[(bm * 8 + h) * 1000 + tqi] = m + logf(e0 + e1);
}

// ============================================================
// LSH output per hash slot (f32, FROZEN): o_lsh[(bm*8+h)*1000+t][d]
// ============================================================
__global__ __launch_bounds__(256)
void k_lsh_out(const float* __restrict__ qk, const float* __restrict__ v,
               const int* __restrict__ st, const int* __restrict__ mask,
               const float* __restrict__ lsebuf, float* __restrict__ o_lsh)
{
    int idx = blockIdx.x * 256 + threadIdx.x;
    if (idx >= 64 * 8000) return;
    const int s = idx % 8000;
    const int bm = idx / 8000;
    const int b = bm >> 2, hs = bm & 3;
    const int c = s / 25;
    const int h = c / 40;
    const int cp = (c + 319) % 320;
    const int* stb = st + bm * 8000;
    const int tqi = stb[s];
    const bool mi = mask[b * kT + tqi] != 0;
    float qr[32];
    {
        const float* q = qk + ((size_t)(b * kT + tqi)) * 256 + (4 + hs) * 32;
        for (int d = 0; d < 32; ++d) qr[d] = q[d];
    }
    const float lse = lsebuf[(bm * 8 + h) * 1000 + tqi];

    float o[32];
    for (int d = 0; d < 32; ++d) o[d] = 0.f;
    for (int j = 0; j < 50; ++j) {
        int slot = (j < 25) ? c * 25 + j : cp * 25 + (j - 25);
        int tj = stb[slot];
        float dv;
        if (tqi == tj)      dv = SELFVF;
        else if (tqi < tj)  dv = MASKVF;
        else {
            bool mj = mask[b * kT + tj] != 0;
            if (!(mi && mj)) dv = MASKVF;
            else {
                const float* kr = qk + ((size_t)(b * kT + tj)) * 256 + (4 + hs) * 32;
                float nm = knorm32(kr);
                dv = dot32_kn(qr, kr, nm) * RSD;
            }
        }
        float p = expf(dv - lse);
        const float* vr = v + ((size_t)(b * kT + tj)) * 256 + (4 + hs) * 32;
        for (int d = 0; d < 32; ++d) o[d] = fmaf(p, vr[d], o[d]);
    }
    float* op = o_lsh + (((size_t)bm * 8 + h) * 1000 + tqi) * 32;
    for (int d = 0; d < 32; ++d) op[d] = o[d];
}

// ============================================================
// Combine 8 hashes (FROZEN) -> attnbuf cols 128..255
// ============================================================
__global__ __launch_bounds__(256)
void k_combine(const float* __restrict__ o_lsh, const float* __restrict__ lsebuf,
               float* __restrict__ attnout)
{
    int idx = blockIdx.x * 256 + threadIdx.x;
    if (idx >= 64 * 1000 * 32) return;
    int d = idx & 31;
    int t = (idx >> 5) % 1000;
    int bm = idx / 32000;
    int b = bm >> 2, hs = bm & 3;
    float l[8];
    float m = -3.4e38f;
    for (int hh = 0; hh < 8; ++hh) {
        l[hh] = lsebuf[(bm * 8 + hh) * 1000 + t];
        m = fmaxf(m, l[hh]);
    }
    float ssum = 0.f;
    for (int hh = 0; hh < 8; ++hh) ssum += expf(l[hh] - m);
    float lse_tot = m + logf(ssum);
    float acc = 0.f;
    for (int hh = 0; hh < 8; ++hh) {
        float w = expf(l[hh] - lse_tot);
        acc = fmaf(w, o_lsh[(((size_t)bm * 8 + hh) * 1000 + t) * 32 + d], acc);
    }
    attnout[((size_t)(b * kT + t)) * 256 + (4 + hs) * 32 + d] = acc;
}

// ============================================================
// Host launcher
// ============================================================
static inline void rowgemm(int epi, const float* A, const float* W,
                           const float* bias, float* C, int M, int N, int K, int ldc,
                           hipStream_t s)
{
    dim3 g(M);
    if (epi == 0)      hipLaunchKernelGGL((k_rowgemm<0>), g, dim3(256), 0, s, A, W, bias, C, N, K, ldc);
    else if (epi == 1) hipLaunchKernelGGL((k_rowgemm<1>), g, dim3(256), 0, s, A, W, bias, C, N, K, ldc);
    else               hipLaunchKernelGGL((k_rowgemm<2>), g, dim3(256), 0, s, A, W, bias, C, N, K, ldc);
}

extern "C" void kernel_launch(void* const* d_in, const int* in_sizes, int n_in,
                              void* d_out, int out_size, void* d_ws, size_t ws_size,
                              hipStream_t stream)
{
    const int*   mcc     = (const int*)d_in[0];
    const int*   amt     = (const int*)d_in[1];
    const int*   cur     = (const int*)d_in[2];
    const float* e_mcc   = (const float*)d_in[3];
    const float* e_amt   = (const float*)d_in[4];
    const float* e_cur   = (const float*)d_in[5];
    const float* proj_w  = (const float*)d_in[6];
    const float* proj_b  = (const float*)d_in[7];
    const float* toqk_w  = (const float*)d_in[8];
    const float* tov_w   = (const float*)d_in[9];
    const float* toout_w = (const float*)d_in[10];
    const float* toout_b = (const float*)d_in[11];
    const float* ff1_w   = (const float*)d_in[12];
    const float* ff1_b   = (const float*)d_in[13];
    const float* ff2_w   = (const float*)d_in[14];
    const float* ff2_b   = (const float*)d_in[15];
    const float* ln1_g   = (const float*)d_in[16];
    const float* ln1_b   = (const float*)d_in[17];
    const float* ln2_g   = (const float*)d_in[18];
    const float* ln2_b   = (const float*)d_in[19];
    const float* rot     = (const float*)d_in[20];
    const float* hw1_mcc = (const float*)d_in[21];
    const float* hb1_mcc = (const float*)d_in[22];
    const float* hw2_mcc = (const float*)d_in[23];
    const float* hb2_mcc = (const float*)d_in[24];
    const float* hw1_amt = (const float*)d_in[25];
    const float* hb1_amt = (const float*)d_in[26];
    const float* hw2_amt = (const float*)d_in[27];
    const float* hb2_amt = (const float*)d_in[28];
    const float* hw1_cur = (const float*)d_in[29];
    const float* hb1_cur = (const float*)d_in[30];
    const float* hw2_cur = (const float*)d_in[31];
    const float* hb2_cur = (const float*)d_in[32];
    float* out = (float*)d_out;

    // ---- workspace carve (~169 MB f32; identical to passing r7) ----
    char* p = (char*)d_ws;
    auto alloc = [&](size_t bytes) -> void* {
        void* r = (void*)p;
        p += (bytes + 255) & ~(size_t)255;
        return r;
    };
    float* xbuf    = (float*)alloc((size_t)kM * 256 * 4);
    float* ybuf    = (float*)alloc((size_t)kM * 256 * 4);
    float* qkbuf   = (float*)alloc((size_t)kM * 256 * 4);
    float* vbuf    = (float*)alloc((size_t)kM * 256 * 4);
    float* attnbuf = (float*)alloc((size_t)kM * 256 * 4);
    float* embbuf  = (float*)alloc((size_t)kM * 112 * 4);
    float* ffh     = (float*)alloc((size_t)kM * 128 * 4);
    float* o_lsh   = (float*)alloc((size_t)64 * 8 * 1000 * 32 * 4);
    float* lsebuf  = (float*)alloc((size_t)64 * 8000 * 4);
    int*   maskbuf = (int*)alloc((size_t)kM * 4);
    int*   bktbuf  = (int*)alloc((size_t)64 * 8000 * 4);
    int*   stbuf   = (int*)alloc((size_t)64 * 8000 * 4);
    (void)ws_size; (void)in_sizes; (void)n_in; (void)out_size;

    // ---- embed + projection(+posenc) ----
    hipLaunchKernelGGL(k_embed, dim3(kM), dim3(128), 0, stream,
                       mcc, amt, cur, e_mcc, e_amt, e_cur, embbuf, maskbuf);
    rowgemm(2, embbuf, proj_w, proj_b, xbuf, kM, 256, 112, 256, stream);

    // ---- layers ----
    for (int l = 0; l < 6; ++l) {
        const float* Wqk = toqk_w + (size_t)l * 256 * 256;
        const float* Wv  = tov_w + (size_t)l * 256 * 256;
        const float* Wo  = toout_w + (size_t)l * 256 * 256;
        const float* bo  = toout_b + (size_t)l * 256;
        const float* W1  = ff1_w + (size_t)l * 256 * 128;
        const float* b1  = ff1_b + (size_t)l * 128;
        const float* W2  = ff2_w + (size_t)l * 128 * 256;
        const float* b2  = ff2_b + (size_t)l * 256;
        const float* rl  = rot + (size_t)l * 32 * 8 * 20;

        rowgemm(0, xbuf, Wqk, nullptr, qkbuf, kM, 256, 256, 256, stream);
        rowgemm(0, xbuf, Wv, nullptr, vbuf, kM, 256, 256, 256, stream);

        hipLaunchKernelGGL(k_local, dim3((64 * 1000 + 255) / 256), dim3(256), 0, stream,
                           qkbuf, vbuf, maskbuf, attnbuf);
        hipLaunchKernelGGL(k_bucket, dim3((64 * 8000 + 255) / 256), dim3(256), 0, stream,
                           qkbuf, rl, bktbuf);
        hipLaunchKernelGGL(k_sortp, dim3(512), dim3(64), 0, stream, bktbuf, stbuf);
        hipLaunchKernelGGL(k_lsh_lse, dim3((64 * 8000 + 255) / 256), dim3(256), 0, stream,
                           qkbuf, stbuf, maskbuf, lsebuf);
        hipLaunchKernelGGL(k_lsh_out, dim3((64 * 8000 + 255) / 256), dim3(256), 0, stream,
                           qkbuf, vbuf, stbuf, maskbuf, lsebuf, o_lsh);
        hipLaunchKernelGGL(k_combine, dim3((64 * 1000 * 32 + 255) / 256), dim3(256), 0, stream,
                           o_lsh, lsebuf, attnbuf);

        rowgemm(0, attnbuf, Wo, bo, ybuf, kM, 256, 256, 256, stream);
        hipLaunchKernelGGL(k_ln, dim3((kM + 255) / 256), dim3(256), 0, stream,
                           xbuf, ybuf, ln1_g + l * 256, ln1_b + l * 256, xbuf);

        rowgemm(1, xbuf, W1, b1, ffh, kM, 128, 256, 128, stream);
        rowgemm(0, ffh, W2, b2, ybuf, kM, 256, 128, 256, stream);
        hipLaunchKernelGGL(k_ln, dim3((kM + 255) / 256), dim3(256), 0, stream,
                           xbuf, ybuf, ln2_g + l * 256, ln2_b + l * 256, xbuf);
    }

    // ---- heads ----
    rowgemm(1, xbuf, hw1_mcc, hb1_mcc, ffh, kM, 128, 256, 128, stream);
    rowgemm(0, ffh, hw2_mcc, hb2_mcc, out + 0, kM, 200, 128, 320, stream);
    rowgemm(1, xbuf, hw1_amt, hb1_amt, ffh, kM, 128, 256, 128, stream);
    rowgemm(0, ffh, hw2_amt, hb2_amt, out + 200, kM, 100, 128, 320, stream);
    rowgemm(1, xbuf, hw1_cur, hb1_cur, ffh, kM, 128, 256, 128, stream);
    rowgemm(0, ffh, hw2_cur, hb2_cur, out + 300, kM, 20, 128, 320, stream);
}

// Round 9
// 5042.968 us; speedup vs baseline: 8.4750x; 1.4327x over previous
//
#include <hip/hip_runtime.h>
#include <cstdint>
#include <cstddef>

static const int kT = 1000;
static const int kM = 16000;          // 16 * 1000 tokens
#define MASKVF (-1000000000.0f)
#define SELFVF (-50000.0f)
#define RSD     0.17677669529663687f  // 32^-0.5

// ============================================================
// Row GEMM (np-f32 mimic), 8 rows per block. Per-output arithmetic
// BIT-IDENTICAL to r7: same stripe-4 FMA chain, same k order, same
// operand values; only the row->block mapping changed (W reuse x8).
// EPI: 0 none, 1 exact GELU (f64 erf), 2 posenc add.
// *** ARITHMETIC FROZEN ***
// ============================================================
template<int EPI, int RPB>
__global__ __launch_bounds__(256)
void k_rowgemm(const float* __restrict__ A, const float* __restrict__ W,
               const float* __restrict__ bias, float* __restrict__ C,
               int N, int K, int ldc)
{
    __shared__ float As[RPB * 256];
    const int row0 = blockIdx.x * RPB;
    const int n = threadIdx.x;
    for (int e = threadIdx.x; e < RPB * K; e += 256) {
        int r = e / K, k = e - r * K;
        As[r * 256 + k] = A[(size_t)(row0 + r) * K + k];
    }
    __syncthreads();
    if (n >= N) return;

    float acc[RPB][4];
#pragma unroll
    for (int r = 0; r < RPB; ++r) {
        acc[r][0] = 0.f; acc[r][1] = 0.f; acc[r][2] = 0.f; acc[r][3] = 0.f;
    }
    int k = 0;
    for (; k + 3 < K; k += 4) {
        float w0 = W[(size_t)(k + 0) * N + n];
        float w1 = W[(size_t)(k + 1) * N + n];
        float w2 = W[(size_t)(k + 2) * N + n];
        float w3 = W[(size_t)(k + 3) * N + n];
#pragma unroll
        for (int r = 0; r < RPB; ++r) {
            const float4 a4 = *(const float4*)&As[r * 256 + k];
            acc[r][0] = fmaf(a4.x, w0, acc[r][0]);
            acc[r][1] = fmaf(a4.y, w1, acc[r][1]);
            acc[r][2] = fmaf(a4.z, w2, acc[r][2]);
            acc[r][3] = fmaf(a4.w, w3, acc[r][3]);
        }
    }
    for (; k < K; ++k) {   // never taken for K in {112,128,256}; kept for exact parity
        float wk = W[(size_t)k * N + n];
#pragma unroll
        for (int r = 0; r < RPB; ++r)
            acc[r][0] = fmaf(As[r * 256 + k], wk, acc[r][0]);
    }

#pragma unroll
    for (int r = 0; r < RPB; ++r) {
        float a = (acc[r][0] + acc[r][1]) + (acc[r][2] + acc[r][3]);
        if (bias) a += bias[n];
        if (EPI == 1) a = 0.5f * a * (1.0f + (float)erf((double)a * 0.7071067811865476));
        if (EPI == 2) {
            int t = (row0 + r) % kT;
            const float cexp = (float)(-9.21034037198 / 256.0);
            float dv = expf((float)(n & ~1) * cexp);
            float arg = (float)t * dv;
            a += (n & 1) ? (float)cos((double)arg) : (float)sin((double)arg);
        }
        C[(size_t)(row0 + r) * ldc + n] = a;
    }
}

// ============================================================
// Embedding gather + mask
// ============================================================
__global__ __launch_bounds__(128)
void k_embed(const int* __restrict__ mcc, const int* __restrict__ amt,
             const int* __restrict__ cur,
             const float* __restrict__ e_mcc, const float* __restrict__ e_amt,
             const float* __restrict__ e_cur,
             float* __restrict__ emb, int* __restrict__ maskbuf)
{
    int tok = blockIdx.x;
    int c = threadIdx.x;
    if (c < 112) {
        float v;
        if (c < 64)       v = e_mcc[mcc[tok] * 64 + c];
        else if (c < 96)  v = e_amt[amt[tok] * 32 + (c - 64)];
        else              v = e_cur[cur[tok] * 16 + (c - 96)];
        emb[(size_t)tok * 112 + c] = v;
    }
    if (c == 0) maskbuf[tok] = (mcc[tok] == 0) ? 1 : 0;
}

// ============================================================
// LayerNorm(x + delta), f32 mimic (FROZEN arithmetic).
// ============================================================
__global__ __launch_bounds__(256)
void k_ln(const float* __restrict__ x, const float* __restrict__ dlt,
          const float* __restrict__ g, const float* __restrict__ b,
          float* __restrict__ out)
{
    int tok = blockIdx.x * 256 + threadIdx.x;
    if (tok >= kM) return;
    const float* xr = x + (size_t)tok * 256;
    const float* dr = dlt + (size_t)tok * 256;
    float s0 = 0.f, s1 = 0.f, s2 = 0.f, s3 = 0.f;
    for (int i = 0; i < 256; i += 4) {
        s0 += xr[i + 0] + dr[i + 0];
        s1 += xr[i + 1] + dr[i + 1];
        s2 += xr[i + 2] + dr[i + 2];
        s3 += xr[i + 3] + dr[i + 3];
    }
    float mean = ((s0 + s1) + (s2 + s3)) / 256.0f;
    float v0 = 0.f, v1 = 0.f, v2 = 0.f, v3 = 0.f;
    for (int i = 0; i < 256; i += 4) {
        float d0 = xr[i + 0] + dr[i + 0] - mean; v0 = fmaf(d0, d0, v0);
        float d1 = xr[i + 1] + dr[i + 1] - mean; v1 = fmaf(d1, d1, v1);
        float d2 = xr[i + 2] + dr[i + 2] - mean; v2 = fmaf(d2, d2, v2);
        float d3 = xr[i + 3] + dr[i + 3] - mean; v3 = fmaf(d3, d3, v3);
    }
    float var = ((v0 + v1) + (v2 + v3)) / 256.0f;
    float denom = sqrtf(var + 1e-5f);
    float* yo = out + (size_t)tok * 256;
    for (int i = 0; i < 256; ++i)
        yo[i] = (xr[i] + dr[i] - mean) / denom * g[i] + b[i];
}

// ============================================================
// f32 helpers (FROZEN chains).
// ============================================================
__device__ inline float knorm32(const float* kr)
{
    float n0 = 0.f, n1 = 0.f, n2 = 0.f, n3 = 0.f;
    for (int d = 0; d < 32; d += 4) {
        n0 = fmaf(kr[d + 0], kr[d + 0], n0);
        n1 = fmaf(kr[d + 1], kr[d + 1], n1);
        n2 = fmaf(kr[d + 2], kr[d + 2], n2);
        n3 = fmaf(kr[d + 3], kr[d + 3], n3);
    }
    return fmaxf(sqrtf((n0 + n1) + (n2 + n3)), 1e-12f);
}

// dot of q with PRE-NORMALIZED key kn (kn[d]==kr[d]/nm, bit-identical
// to r7's inline kr[d]/nm operands).
__device__ inline float dot32(const float* q, const float* kn)
{
    float a0 = 0.f, a1 = 0.f, a2 = 0.f, a3 = 0.f;
    for (int d = 0; d < 32; d += 4) {
        a0 = fmaf(q[d + 0], kn[d + 0], a0);
        a1 = fmaf(q[d + 1], kn[d + 1], a1);
        a2 = fmaf(q[d + 2], kn[d + 2], a2);
        a3 = fmaf(q[d + 3], kn[d + 3], a3);
    }
    return (a0 + a1) + (a2 + a3);
}

// ============================================================
// Per-(token, head) key normalization memo: kn = k / max(||k||,1e-12).
// Same f32 ops as the former per-pair computation -> same bits.
// ============================================================
__global__ __launch_bounds__(256)
void k_knorm(const float* __restrict__ qk, float* __restrict__ kn)
{
    int idx = blockIdx.x * 256 + threadIdx.x;
    if (idx >= kM * 8) return;
    int h = idx & 7;
    int tok = idx >> 3;
    const float* kr = qk + (size_t)tok * 256 + h * 32;
    float nm = knorm32(kr);
    float* o = kn + (size_t)tok * 256 + h * 32;
    for (int d = 0; d < 32; ++d) o[d] = kr[d] / nm;
}

// ============================================================
// Local attention (FROZEN): one thread per (bm, ti); keys via kn memo.
// ============================================================
__global__ __launch_bounds__(256)
void k_local(const float* __restrict__ qk, const float* __restrict__ kn,
             const float* __restrict__ v,
             const int* __restrict__ mask, float* __restrict__ attnout)
{
    int idx = blockIdx.x * 256 + threadIdx.x;
    if (idx >= 64 * 1000) return;
    const int ti = idx % 1000;
    const int bm = idx / 1000;
    const int b = bm >> 2, h = bm & 3;
    const int wi = ti / 50;
    const bool mi = mask[b * kT + ti] != 0;

    float qs[32];
    {
        const float* qr = qk + ((size_t)(b * kT + ti)) * 256 + h * 32;
        for (int d = 0; d < 32; ++d) qs[d] = qr[d] * RSD;
    }

    auto tj_of = [&](int j) -> int {
        if (j < 50) return (wi > 0) ? (wi - 1) * 50 + j : -1;
        return wi * 50 + (j - 50);
    };
    auto dval = [&](int j) -> float {
        int tj = tj_of(j);
        bool mj = (tj >= 0) && (mask[b * kT + tj] != 0);
        if (!(mi && mj)) return MASKVF;
        if (tj < 0)      return MASKVF;
        if (ti == tj)    return SELFVF;
        if (ti < tj)     return MASKVF;
        return dot32(qs, kn + ((size_t)(b * kT + tj)) * 256 + h * 32);
    };

    float m = -3.4e38f;
    for (int j = 0; j < 100; ++j) m = fmaxf(m, dval(j));
    float e0 = 0.f, e1 = 0.f, e2 = 0.f, e3 = 0.f;
    for (int j = 0; j < 100; j += 4) {
        e0 += expf(dval(j + 0) - m);
        e1 += expf(dval(j + 1) - m);
        e2 += expf(dval(j + 2) - m);
        e3 += expf(dval(j + 3) - m);
    }
    float ssum = (e0 + e1) + (e2 + e3);

    float o[32];
    for (int d = 0; d < 32; ++d) o[d] = 0.f;
    for (int j = 0; j < 100; ++j) {
        float p = expf(dval(j) - m) / ssum;
        int tj = tj_of(j);
        if (tj >= 0) {
            const float* vr = v + ((size_t)(b * kT + tj)) * 256 + h * 32;
            for (int d = 0; d < 32; ++d) o[d] = fmaf(p, vr[d], o[d]);
        }
    }
    float* op = attnout + ((size_t)(b * kT + ti)) * 256 + h * 32;
    for (int d = 0; d < 32; ++d) op[d] = o[d];
}

// ============================================================
// LSH bucketing (FROZEN): one thread per (bm, h, t).
// ============================================================
__global__ __launch_bounds__(256)
void k_bucket(const float* __restrict__ qk, const float* __restrict__ rot,
              int* __restrict__ bkt)
{
    int idx = blockIdx.x * 256 + threadIdx.x;
    if (idx >= 64 * 8 * 1000) return;
    const int t = idx % 1000;
    const int h = (idx / 1000) & 7;
    const int bm = idx / 8000;
    const int b = bm >> 2, hs = bm & 3;
    const float* q = qk + ((size_t)(b * kT + t)) * 256 + (4 + hs) * 32;
    float qr[32];
    for (int d = 0; d < 32; ++d) qr[d] = q[d];
    float s[20];
    for (int r = 0; r < 20; ++r) {
        float a0 = 0.f, a1 = 0.f, a2 = 0.f, a3 = 0.f;
        for (int d = 0; d < 32; d += 4) {
            a0 = fmaf(qr[d + 0], rot[(d + 0) * 160 + h * 20 + r], a0);
            a1 = fmaf(qr[d + 1], rot[(d + 1) * 160 + h * 20 + r], a1);
            a2 = fmaf(qr[d + 2], rot[(d + 2) * 160 + h * 20 + r], a2);
            a3 = fmaf(qr[d + 3], rot[(d + 3) * 160 + h * 20 + r], a3);
        }
        s[r] = (a0 + a1) + (a2 + a3);
    }
    float best = -3.4e38f; int bi = 0;
    for (int r = 0; r < 40; ++r) {
        float val = (r < 20) ? s[r] : -s[r - 20];
        if (val > best) { best = val; bi = r; }
    }
    bkt[(bm * 8 + h) * 1000 + t] = bi;
}

// ============================================================
// Counting sort per (bm, h): parallel LDS, bit-identical permutation.
// ============================================================
__global__ __launch_bounds__(64)
void k_sortp(const int* __restrict__ bkt, int* __restrict__ st)
{
    __shared__ int lb[1000];
    __shared__ int cnt[40];
    __shared__ int offs[40];
    const int bh = blockIdx.x;   // 0..511
    const int* src = bkt + bh * 1000;
    for (int i = threadIdx.x; i < 1000; i += 64) lb[i] = src[i];
    if (threadIdx.x < 40) cnt[threadIdx.x] = 0;
    __syncthreads();
    for (int i = threadIdx.x; i < 1000; i += 64) atomicAdd(&cnt[lb[i]], 1);
    __syncthreads();
    if (threadIdx.x == 0) {
        int a = 0;
        for (int q = 0; q < 40; ++q) { offs[q] = a; a += cnt[q]; }
    }
    __syncthreads();
    if (threadIdx.x < 40) {
        const int beta = threadIdx.x;
        int off = offs[beta];
        int* dst = st + bh * 1000;
        for (int t = 0; t < 1000; ++t)
            if (lb[t] == beta) dst[off++] = t;
    }
}

// ============================================================
// LSH lse (FROZEN): one thread per (bm, slot); keys via kn memo.
// ============================================================
__global__ __launch_bounds__(256)
void k_lsh_lse(const float* __restrict__ qk, const float* __restrict__ kn,
               const int* __restrict__ st,
               const int* __restrict__ mask, float* __restrict__ lsebuf)
{
    int idx = blockIdx.x * 256 + threadIdx.x;
    if (idx >= 64 * 8000) return;
    const int s = idx % 8000;
    const int bm = idx / 8000;
    const int b = bm >> 2, hs = bm & 3;
    const int c = s / 25;
    const int h = c / 40;
    const int cp = (c + 319) % 320;
    const int* stb = st + bm * 8000;
    const int tqi = stb[s];
    const bool mi = mask[b * kT + tqi] != 0;
    float qr[32];
    {
        const float* q = qk + ((size_t)(b * kT + tqi)) * 256 + (4 + hs) * 32;
        for (int d = 0; d < 32; ++d) qr[d] = q[d];
    }

    auto dval = [&](int j) -> float {
        int slot = (j < 25) ? c * 25 + j : cp * 25 + (j - 25);
        int tj = stb[slot];
        if (tqi == tj) return SELFVF;
        if (tqi < tj)  return MASKVF;
        bool mj = mask[b * kT + tj] != 0;
        if (!(mi && mj)) return MASKVF;
        return dot32(qr, kn + ((size_t)(b * kT + tj)) * 256 + (4 + hs) * 32) * RSD;
    };

    float m = -3.4e38f;
    for (int j = 0; j < 50; ++j) m = fmaxf(m, dval(j));
    float e0 = 0.f, e1 = 0.f;
    for (int j = 0; j < 50; j += 2) {
        e0 += expf(dval(j + 0) - m);
        e1 += expf(dval(j + 1) - m);
    }
    lsebuf[(bm * 8 + h) * 1000 + tqi] = m + logf(e0 + e1);
}

// ============================================================
// LSH output per hash slot (FROZEN): keys via kn memo.
// ============================================================
__global__ __launch_bounds__(256)
void k_lsh_out(const float* __restrict__ qk, const float* __restrict__ kn,
               const float* __restrict__ v,
               const int* __restrict__ st, const int* __restrict__ mask,
               const float* __restrict__ lsebuf, float* __restrict__ o_lsh)
{
    int idx = blockIdx.x * 256 + threadIdx.x;
    if (idx >= 64 * 8000) return;
    const int s = idx % 8000;
    const int bm = idx / 8000;
    const int b = bm >> 2, hs = bm & 3;
    const int c = s / 25;
    const int h = c / 40;
    const int cp = (c + 319) % 320;
    const int* stb = st + bm * 8000;
    const int tqi = stb[s];
    const bool mi = mask[b * kT + tqi] != 0;
    float qr[32];
    {
        const float* q = qk + ((size_t)(b * kT + tqi)) * 256 + (4 + hs) * 32;
        for (int d = 0; d < 32; ++d) qr[d] = q[d];
    }
    const float lse = lsebuf[(bm * 8 + h) * 1000 + tqi];

    float o[32];
    for (int d = 0; d < 32; ++d) o[d] = 0.f;
    for (int j = 0; j < 50; ++j) {
        int slot = (j < 25) ? c * 25 + j : cp * 25 + (j - 25);
        int tj = stb[slot];
        float dv;
        if (tqi == tj)      dv = SELFVF;
        else if (tqi < tj)  dv = MASKVF;
        else {
            bool mj = mask[b * kT + tj] != 0;
            if (!(mi && mj)) dv = MASKVF;
            else dv = dot32(qr, kn + ((size_t)(b * kT + tj)) * 256 + (4 + hs) * 32) * RSD;
        }
        float p = expf(dv - lse);
        const float* vr = v + ((size_t)(b * kT + tj)) * 256 + (4 + hs) * 32;
        for (int d = 0; d < 32; ++d) o[d] = fmaf(p, vr[d], o[d]);
    }
    float* op = o_lsh + (((size_t)bm * 8 + h) * 1000 + tqi) * 32;
    for (int d = 0; d < 32; ++d) op[d] = o[d];
}

// ============================================================
// Combine 8 hashes (FROZEN) -> attnbuf cols 128..255
// ============================================================
__global__ __launch_bounds__(256)
void k_combine(const float* __restrict__ o_lsh, const float* __restrict__ lsebuf,
               float* __restrict__ attnout)
{
    int idx = blockIdx.x * 256 + threadIdx.x;
    if (idx >= 64 * 1000 * 32) return;
    int d = idx & 31;
    int t = (idx >> 5) % 1000;
    int bm = idx / 32000;
    int b = bm >> 2, hs = bm & 3;
    float l[8];
    float m = -3.4e38f;
    for (int hh = 0; hh < 8; ++hh) {
        l[hh] = lsebuf[(bm * 8 + hh) * 1000 + t];
        m = fmaxf(m, l[hh]);
    }
    float ssum = 0.f;
    for (int hh = 0; hh < 8; ++hh) ssum += expf(l[hh] - m);
    float lse_tot = m + logf(ssum);
    float acc = 0.f;
    for (int hh = 0; hh < 8; ++hh) {
        float w = expf(l[hh] - lse_tot);
        acc = fmaf(w, o_lsh[(((size_t)bm * 8 + hh) * 1000 + t) * 32 + d], acc);
    }
    attnout[((size_t)(b * kT + t)) * 256 + (4 + hs) * 32 + d] = acc;
}

// ============================================================
// Host launcher
// ============================================================
static inline void rowgemm(int epi, const float* A, const float* W,
                           const float* bias, float* C, int M, int N, int K, int ldc,
                           hipStream_t s)
{
    const int RPB = 8;
    dim3 g(M / RPB);
    if (epi == 0)      hipLaunchKernelGGL((k_rowgemm<0, RPB>), g, dim3(256), 0, s, A, W, bias, C, N, K, ldc);
    else if (epi == 1) hipLaunchKernelGGL((k_rowgemm<1, RPB>), g, dim3(256), 0, s, A, W, bias, C, N, K, ldc);
    else               hipLaunchKernelGGL((k_rowgemm<2, RPB>), g, dim3(256), 0, s, A, W, bias, C, N, K, ldc);
}

extern "C" void kernel_launch(void* const* d_in, const int* in_sizes, int n_in,
                              void* d_out, int out_size, void* d_ws, size_t ws_size,
                              hipStream_t stream)
{
    const int*   mcc     = (const int*)d_in[0];
    const int*   amt     = (const int*)d_in[1];
    const int*   cur     = (const int*)d_in[2];
    const float* e_mcc   = (const float*)d_in[3];
    const float* e_amt   = (const float*)d_in[4];
    const float* e_cur   = (const float*)d_in[5];
    const float* proj_w  = (const float*)d_in[6];
    const float* proj_b  = (const float*)d_in[7];
    const float* toqk_w  = (const float*)d_in[8];
    const float* tov_w   = (const float*)d_in[9];
    const float* toout_w = (const float*)d_in[10];
    const float* toout_b = (const float*)d_in[11];
    const float* ff1_w   = (const float*)d_in[12];
    const float* ff1_b   = (const float*)d_in[13];
    const float* ff2_w   = (const float*)d_in[14];
    const float* ff2_b   = (const float*)d_in[15];
    const float* ln1_g   = (const float*)d_in[16];
    const float* ln1_b   = (const float*)d_in[17];
    const float* ln2_g   = (const float*)d_in[18];
    const float* ln2_b   = (const float*)d_in[19];
    const float* rot     = (const float*)d_in[20];
    const float* hw1_mcc = (const float*)d_in[21];
    const float* hb1_mcc = (const float*)d_in[22];
    const float* hw2_mcc = (const float*)d_in[23];
    const float* hb2_mcc = (const float*)d_in[24];
    const float* hw1_amt = (const float*)d_in[25];
    const float* hb1_amt = (const float*)d_in[26];
    const float* hw2_amt = (const float*)d_in[27];
    const float* hb2_amt = (const float*)d_in[28];
    const float* hw1_cur = (const float*)d_in[29];
    const float* hb1_cur = (const float*)d_in[30];
    const float* hw2_cur = (const float*)d_in[31];
    const float* hb2_cur = (const float*)d_in[32];
    float* out = (float*)d_out;

    // ---- workspace carve (identical to passing r7/r8 budget) ----
    char* p = (char*)d_ws;
    auto alloc = [&](size_t bytes) -> void* {
        void* r = (void*)p;
        p += (bytes + 255) & ~(size_t)255;
        return r;
    };
    float* xbuf    = (float*)alloc((size_t)kM * 256 * 4);
    float* ybuf    = (float*)alloc((size_t)kM * 256 * 4);
    float* qkbuf   = (float*)alloc((size_t)kM * 256 * 4);
    float* vbuf    = (float*)alloc((size_t)kM * 256 * 4);
    float* attnbuf = (float*)alloc((size_t)kM * 256 * 4);
    float* embbuf  = (float*)alloc((size_t)kM * 112 * 4);
    float* ffh     = (float*)alloc((size_t)kM * 128 * 4);
    float* o_lsh   = (float*)alloc((size_t)64 * 8 * 1000 * 32 * 4);
    float* lsebuf  = (float*)alloc((size_t)64 * 8000 * 4);
    int*   maskbuf = (int*)alloc((size_t)kM * 4);
    int*   bktbuf  = (int*)alloc((size_t)64 * 8000 * 4);
    int*   stbuf   = (int*)alloc((size_t)64 * 8000 * 4);
    // kn memo aliases ybuf: ybuf is only written AFTER the attention
    // phase (Wo GEMM / FF GEMM), and kn is consumed before those.
    float* knbuf   = ybuf;
    (void)ws_size; (void)in_sizes; (void)n_in; (void)out_size;

    // ---- embed + projection(+posenc) ----
    hipLaunchKernelGGL(k_embed, dim3(kM), dim3(128), 0, stream,
                       mcc, amt, cur, e_mcc, e_amt, e_cur, embbuf, maskbuf);
    rowgemm(2, embbuf, proj_w, proj_b, xbuf, kM, 256, 112, 256, stream);

    // ---- layers ----
    for (int l = 0; l < 6; ++l) {
        const float* Wqk = toqk_w + (size_t)l * 256 * 256;
        const float* Wv  = tov_w + (size_t)l * 256 * 256;
        const float* Wo  = toout_w + (size_t)l * 256 * 256;
        const float* bo  = toout_b + (size_t)l * 256;
        const float* W1  = ff1_w + (size_t)l * 256 * 128;
        const float* b1  = ff1_b + (size_t)l * 128;
        const float* W2  = ff2_w + (size_t)l * 128 * 256;
        const float* b2  = ff2_b + (size_t)l * 256;
        const float* rl  = rot + (size_t)l * 32 * 8 * 20;

        rowgemm(0, xbuf, Wqk, nullptr, qkbuf, kM, 256, 256, 256, stream);
        rowgemm(0, xbuf, Wv, nullptr, vbuf, kM, 256, 256, 256, stream);

        hipLaunchKernelGGL(k_knorm, dim3((kM * 8 + 255) / 256), dim3(256), 0, stream,
                           qkbuf, knbuf);
        hipLaunchKernelGGL(k_local, dim3((64 * 1000 + 255) / 256), dim3(256), 0, stream,
                           qkbuf, knbuf, vbuf, maskbuf, attnbuf);
        hipLaunchKernelGGL(k_bucket, dim3((64 * 8000 + 255) / 256), dim3(256), 0, stream,
                           qkbuf, rl, bktbuf);
        hipLaunchKernelGGL(k_sortp, dim3(512), dim3(64), 0, stream, bktbuf, stbuf);
        hipLaunchKernelGGL(k_lsh_lse, dim3((64 * 8000 + 255) / 256), dim3(256), 0, stream,
                           qkbuf, knbuf, stbuf, maskbuf, lsebuf);
        hipLaunchKernelGGL(k_lsh_out, dim3((64 * 8000 + 255) / 256), dim3(256), 0, stream,
                           qkbuf, knbuf, vbuf, stbuf, maskbuf, lsebuf, o_lsh);
        hipLaunchKernelGGL(k_combine, dim3((64 * 1000 * 32 + 255) / 256), dim3(256), 0, stream,
                           o_lsh, lsebuf, attnbuf);

        rowgemm(0, attnbuf, Wo, bo, ybuf, kM, 256, 256, 256, stream);
        hipLaunchKernelGGL(k_ln, dim3((kM + 255) / 256), dim3(256), 0, stream,
                           xbuf, ybuf, ln1_g + l * 256, ln1_b + l * 256, xbuf);

        rowgemm(1, xbuf, W1, b1, ffh, kM, 128, 256, 128, stream);
        rowgemm(0, ffh, W2, b2, ybuf, kM, 256, 128, 256, stream);
        hipLaunchKernelGGL(k_ln, dim3((kM + 255) / 256), dim3(256), 0, stream,
                           xbuf, ybuf, ln2_g + l * 256, ln2_b + l * 256, xbuf);
    }

    // ---- heads ----
    rowgemm(1, xbuf, hw1_mcc, hb1_mcc, ffh, kM, 128, 256, 128, stream);
    rowgemm(0, ffh, hw2_mcc, hb2_mcc, out + 0, kM, 200, 128, 320, stream);
    rowgemm(1, xbuf, hw1_amt, hb1_amt, ffh, kM, 128, 256, 128, stream);
    rowgemm(0, ffh, hw2_amt, hb2_amt, out + 200, kM, 100, 128, 320, stream);
    rowgemm(1, xbuf, hw1_cur, hb1_cur, ffh, kM, 128, 256, 128, stream);
    rowgemm(0, ffh, hw2_cur, hb2_cur, out + 300, kM, 20, 128, 320, stream);
}